// Round 1
// 414.604 us; speedup vs baseline: 1.0524x; 1.0524x over previous
//
#include <hip/hip_runtime.h>
#include <cstdint>
#include <cstddef>

#define T_SEQ 512
#define BATCH 64
#define IN_SZ 512
#define HID   1024
#define BH    (BATCH*HID)      /* 65536 */
#define M_TOT (T_SEQ*BATCH)    /* 32768 */
#define D_CH  16               /* scan chunk depth */

typedef float f32x4 __attribute__((ext_vector_type(4)));
typedef _Float16 f16x8 __attribute__((ext_vector_type(8)));

__device__ inline unsigned short f2h(float f){
  union { _Float16 h; unsigned short u; } v;
  v.h = (_Float16)f;            // RTNE
  return v.u;
}
__device__ inline float h2f(unsigned short s){
  union { unsigned short u; _Float16 h; } v; v.u = s;
  return (float)v.h;
}

__device__ inline float sigm_f(float x){ return 1.f/(1.f + __expf(-x)); }
__device__ inline float tanh_f(float x){ float e = __expf(2.f*x); return 1.f - 2.f/(e + 1.f); }

// async global->LDS, 16B per lane; lds base must be wave-uniform
__device__ inline void async16(const void* g, void* l){
  __builtin_amdgcn_global_load_lds(
      (__attribute__((address_space(1))) void*)g,
      (__attribute__((address_space(3))) void*)l,
      16, 0, 0);
}

// ---------- fused fp32 -> fp16 conversion for x, Uc, Ua, Uh ----------
#define XBLK 16384
__global__ __launch_bounds__(256) void cvt_all(
    const float* __restrict__ x,  const float* __restrict__ Uc,
    const float* __restrict__ Ua, const float* __restrict__ Uh,
    unsigned short* __restrict__ xb, unsigned short* __restrict__ U0,
    unsigned short* __restrict__ U1, unsigned short* __restrict__ U2)
{
  int b = blockIdx.x;
  const float* in; unsigned short* out; int i;
  if (b < XBLK){
    in = x; out = xb; i = b*256 + threadIdx.x;
  } else {
    int r = b - XBLK;
    int which = r >> 9;            // 0..2
    int lb = r & 511;
    i = lb*256 + threadIdx.x;
    in  = (which==0) ? Uc : (which==1) ? Ua : Uh;
    out = (which==0) ? U0 : (which==1) ? U1 : U2;
  }
  float4 v = ((const float4*)in)[i];
  ushort4 o;
  o.x = f2h(v.x); o.y = f2h(v.y); o.z = f2h(v.z); o.w = f2h(v.w);
  ((ushort4*)out)[i] = o;
}

// ---------- fused 3-projection GEMM: 256x256 tile, BK=64, 8 waves, phase-interleaved ----
// A = x_f16 [M_TOT, IN_SZ]; B^T = U [HID, IN_SZ].
// Grid 1536 = 8 xcd * 16 mb * (4 nb * 3 z). XCD-bijective: xcd=bid&7 owns mb in
// [xcd*16, +16); 12 inner slots per mb share one 256KB A panel; all 12 U panels
// (3MB fp16) stay L2-resident per XCD.
//
// LDS (128 KiB): A slots [buf][kh] = 16KB each at ((buf*2+kh)<<14); B at +65536.
// Slot = [256 rows][32 k] fp16, row stride 64B, 4 chunks of 16B per row,
// XOR-swizzle: chunk_lds = chunk_k ^ ((row>>1)&3)  (<=2-way bank conflict, free).
// global_load_lds writes linearly; swizzle is pre-applied on the per-lane GLOBAL
// source address (rule: both-sides-or-neither).
//
// Schedule per group g (consumes K-tile g, buf=g&1), 4 phases:
//   p1: read A(buf,klo) 8 frags + B(buf,klo) n01 | stage Bkhi(g+1) | bar|lgkm0|16 MFMA|bar
//   p2: read B(buf,klo) n23                      | stage Aklo(g+2) | vmcnt(10)|bar|...|bar
//   p3: read A(buf,khi) 8 frags + B(buf,khi) n01 | stage Bklo(g+2) | bar|...|bar
//   p4: read B(buf,khi) n23                      | stage Akhi(g+2) | vmcnt(10)|bar|...|bar
// Each slot is staged exactly one phase after its last read (safe: barrier2 +
// lgkmcnt(0) order). vmcnt(10) = 5 half-tiles (10 loads) in flight across the
// barrier; tail groups use vmcnt(8)/(4)/(0) so every needed half-tile is proven
// landed before its first read. Prologue stages 7 half-tiles, vmcnt(10).
__global__ __launch_bounds__(512, 2) void gemm3(
    const unsigned short* __restrict__ xb,
    const unsigned short* __restrict__ U0,
    const unsigned short* __restrict__ U1,
    const unsigned short* __restrict__ U2,
    const float* __restrict__ b0, const float* __restrict__ b1, const float* __restrict__ b2,
    unsigned short* out0, unsigned short* out1, void* out2, int ph_f16)
{
  __shared__ __align__(16) unsigned char smem_raw[131072];

  const int tid  = threadIdx.x;
  const int wave = tid >> 6, lane = tid & 63;
  const int quad = lane >> 4, l16 = lane & 15;

  const int bid  = blockIdx.x;          // 0..1535
  const int xcd  = bid & 7;
  const int slot = bid >> 3;            // 0..191
  const int mbl  = slot / 12;           // 0..15
  const int inner= slot - mbl*12;       // 0..11
  const int mb   = xcd*16 + mbl;        // 0..127
  const int z    = inner % 3;
  const int nb   = inner / 3;           // 0..3

  const int m0 = mb * 256, n0 = nb * 256;
  const unsigned short* Um = (z==0) ? U0 : (z==1) ? U1 : U2;
  const float* bias        = (z==0) ? b0 : (z==1) ? b1 : b2;
  const int wm = wave >> 2, wn = wave & 3;   // 2 x 4 wave grid; per-wave 128x64

  // staging lane constants: issue covers 16 rows x 64B; row = base16 + (lane>>2),
  // lds chunk = lane&3, source k-chunk = (lane&3) ^ ((lane>>3)&3)
  const int laneRow = lane >> 2;
  const int cg8     = ((lane & 3) ^ ((lane >> 3) & 3)) << 3;
  const unsigned short* srcA = xb + (size_t)m0 * IN_SZ;
  const unsigned short* srcB = Um + (size_t)n0 * IN_SZ;

  // ds-read lane constant: row=R0+l16 -> byte l16*64 + (quad ^ ((l16>>1)&3))*16
  const int cxa = l16*64 + ((quad ^ ((l16 >> 1) & 3)) << 4);

  auto stageA = [&](int tile, int kh){
    unsigned char* dst = smem_raw + (((tile & 1)*2 + kh) << 14);
#pragma unroll
    for (int j = 0; j < 2; ++j){
      const unsigned short* g = srcA + (size_t)((wave*2 + j)*16 + laneRow)*IN_SZ
                                + tile*64 + kh*32 + cg8;
      async16(g, dst + (wave*2 + j)*1024);
    }
  };
  auto stageB = [&](int tile, int kh){
    unsigned char* dst = smem_raw + 65536 + (((tile & 1)*2 + kh) << 14);
#pragma unroll
    for (int j = 0; j < 2; ++j){
      const unsigned short* g = srcB + (size_t)((wave*2 + j)*16 + laneRow)*IN_SZ
                                + tile*64 + kh*32 + cg8;
      async16(g, dst + (wave*2 + j)*1024);
    }
  };

  const f32x4 zf = {0.f, 0.f, 0.f, 0.f};
  f32x4 acc[8][4];
#pragma unroll
  for (int i = 0; i < 8; ++i)
#pragma unroll
    for (int j = 0; j < 4; ++j) acc[i][j] = zf;

  // prologue: Aklo0 Bklo0 Akhi0 Bkhi0 Aklo1 Bklo1 Akhi1 (14 loads); first 4 must land
  stageA(0,0); stageB(0,0); stageA(0,1); stageB(0,1);
  stageA(1,0); stageB(1,0); stageA(1,1);
  asm volatile("s_waitcnt vmcnt(10)" ::: "memory");
  __builtin_amdgcn_s_barrier();

#define CLUSTER(B0_, B1_, N0_, N1_)                                                      \
  __builtin_amdgcn_s_barrier();                                                          \
  asm volatile("s_waitcnt lgkmcnt(0)" ::: "memory");                                     \
  __builtin_amdgcn_s_setprio(1);                                                         \
  _Pragma("unroll")                                                                      \
  for (int im_ = 0; im_ < 8; ++im_){                                                     \
    acc[im_][N0_] = __builtin_amdgcn_mfma_f32_16x16x32_f16(a0[im_], B0_, acc[im_][N0_], 0,0,0); \
    acc[im_][N1_] = __builtin_amdgcn_mfma_f32_16x16x32_f16(a0[im_], B1_, acc[im_][N1_], 0,0,0); \
  }                                                                                      \
  __builtin_amdgcn_s_setprio(0);                                                         \
  __builtin_amdgcn_s_barrier();

  f16x8 a0[8];
#pragma unroll
  for (int g = 0; g < 8; ++g){
    const int buf = g & 1;
    const unsigned char* Ab0 = smem_raw + ((buf*2 + 0) << 14);
    const unsigned char* Ab1 = smem_raw + ((buf*2 + 1) << 14);
    const unsigned char* Bb0 = smem_raw + 65536 + ((buf*2 + 0) << 14);
    const unsigned char* Bb1 = smem_raw + 65536 + ((buf*2 + 1) << 14);

    // ---- p1: ks0, n-frags 0,1
#pragma unroll
    for (int im = 0; im < 8; ++im)
      a0[im] = *(const f16x8*)(Ab0 + wm*8192 + im*1024 + cxa);
    f16x8 q0 = *(const f16x8*)(Bb0 + wn*4096 + 0*1024 + cxa);
    f16x8 q1 = *(const f16x8*)(Bb0 + wn*4096 + 1*1024 + cxa);
    if (g < 7) stageB(g+1, 1);
    CLUSTER(q0, q1, 0, 1)

    // ---- p2: ks0, n-frags 2,3
    f16x8 q2 = *(const f16x8*)(Bb0 + wn*4096 + 2*1024 + cxa);
    f16x8 q3 = *(const f16x8*)(Bb0 + wn*4096 + 3*1024 + cxa);
    if (g < 6) stageA(g+2, 0);
    if (g < 6)      { asm volatile("s_waitcnt vmcnt(10)" ::: "memory"); }
    else if (g == 6){ asm volatile("s_waitcnt vmcnt(8)"  ::: "memory"); }
    else            { asm volatile("s_waitcnt vmcnt(0)"  ::: "memory"); }
    CLUSTER(q2, q3, 2, 3)

    // ---- p3: ks1, n-frags 0,1
#pragma unroll
    for (int im = 0; im < 8; ++im)
      a0[im] = *(const f16x8*)(Ab1 + wm*8192 + im*1024 + cxa);
    q0 = *(const f16x8*)(Bb1 + wn*4096 + 0*1024 + cxa);
    q1 = *(const f16x8*)(Bb1 + wn*4096 + 1*1024 + cxa);
    if (g < 6) stageB(g+2, 0);
    CLUSTER(q0, q1, 0, 1)

    // ---- p4: ks1, n-frags 2,3
    q2 = *(const f16x8*)(Bb1 + wn*4096 + 2*1024 + cxa);
    q3 = *(const f16x8*)(Bb1 + wn*4096 + 3*1024 + cxa);
    if (g < 6) stageA(g+2, 1);
    if (g < 6)      { asm volatile("s_waitcnt vmcnt(10)" ::: "memory"); }
    else if (g == 6){ asm volatile("s_waitcnt vmcnt(4)"  ::: "memory"); }
    CLUSTER(q2, q3, 2, 3)
  }
#undef CLUSTER

  // ---------------- epilogue ----------------
  // C/D layout: row = quad*4 + reg, col = l16 (per verified convention)
  float bv[4];
#pragma unroll
  for (int in = 0; in < 4; ++in) bv[in] = bias[n0 + wn*64 + in*16 + l16];

  if (z == 2 && !ph_f16) {
    float* o32 = (float*)out2;
#pragma unroll
    for (int im = 0; im < 8; ++im)
#pragma unroll
      for (int r = 0; r < 4; ++r){
        int grow = m0 + wm*128 + im*16 + quad*4 + r;
        size_t rb = (size_t)grow * HID;
#pragma unroll
        for (int in = 0; in < 4; ++in)
          o32[rb + n0 + wn*64 + in*16 + l16] = acc[im][in][r] + bv[in];
      }
    return;
  }

  unsigned short* op = (z==0) ? out0 : (z==1) ? out1 : (unsigned short*)out2;
  // per-wave private LDS transpose region: 64 rows x 72 ushorts (144B stride)
  unsigned short* sw = (unsigned short*)smem_raw + wave*4608;
#pragma unroll
  for (int h = 0; h < 2; ++h){
#pragma unroll
    for (int i4 = 0; i4 < 4; ++i4){
      int im = h*4 + i4;
#pragma unroll
      for (int r = 0; r < 4; ++r){
        int lr = i4*16 + quad*4 + r;
#pragma unroll
        for (int in = 0; in < 4; ++in)
          sw[lr*72 + in*16 + l16] = f2h(acc[im][in][r] + bv[in]);
      }
    }
    asm volatile("s_waitcnt lgkmcnt(0)" ::: "memory");   // writes before reads (wave-local)
#pragma unroll
    for (int i = 0; i < 8; ++i){
      int lr = i*8 + (lane >> 3);
      int ch = lane & 7;
      uint4 v = *(const uint4*)(sw + lr*72 + ch*8);
      int grow = m0 + wm*128 + h*64 + lr;
      *(uint4*)(op + (size_t)grow*HID + n0 + wn*64 + ch*8) = v;
    }
    if (h == 0) asm volatile("s_waitcnt lgkmcnt(0)" ::: "memory"); // reads before h=1 writes
  }
}

// ---------- elementwise recurrence: one thread per (b,h), chunked register pipeline ----
template <bool PH16>
__global__ __launch_bounds__(256) void scan_k(
    const unsigned short* __restrict__ pc, const unsigned short* __restrict__ pa,
    const void* __restrict__ phv,
    float* __restrict__ y,
    const float* __restrict__ h0, const float* __restrict__ wc, const float* __restrict__ wa,
    float* __restrict__ hlast)
{
  const int idx  = blockIdx.x * 256 + threadIdx.x;   // 0..65535
  const int hidx = idx & (HID - 1);
  float h = h0[idx];
  const float wcv = wc[hidx], wav = wa[hidx];
  const unsigned short* ph16 = (const unsigned short*)phv;
  const float*          ph32 = (const float*)phv;

  unsigned short cpc[D_CH], cpa[D_CH];
  unsigned short npc[D_CH], npa[D_CH];
  float cph[D_CH], nph[D_CH];
  unsigned short cph16[D_CH], nph16[D_CH];

#pragma unroll
  for (int i = 0; i < D_CH; i++){
    size_t b = (size_t)i*BH + idx;
    cpc[i] = pc[b]; cpa[i] = pa[b];
    if (PH16) cph16[i] = ph16[b]; else cph[i] = ph32[b];
  }

  constexpr int NC = T_SEQ / D_CH;
  for (int c = 0; c < NC; c++){
    const int t0 = c * D_CH;
    if (c + 1 < NC){
#pragma unroll
      for (int i = 0; i < D_CH; i++){
        size_t b = (size_t)(t0 + D_CH + i)*BH + idx;
        npc[i] = pc[b]; npa[i] = pa[b];
        if (PH16) nph16[i] = ph16[b]; else nph[i] = ph32[b];
      }
    }
#pragma unroll
    for (int i = 0; i < D_CH; i++){
      float pcv = h2f(cpc[i]);
      float pav = h2f(cpa[i]);
      float phv_ = PH16 ? h2f(cph16[i]) : cph[i];
      float cc = sigm_f(pcv + wcv*h);
      float a  = 1.f + tanh_f(pav + wav*h);
      float hc = tanh_f(phv_ + a*h);
      h = cc*h + (1.f - cc)*hc;
      y[(size_t)(t0 + i)*BH + idx] = h;
    }
    if (c + 1 < NC){
#pragma unroll
      for (int i = 0; i < D_CH; i++){
        cpc[i] = npc[i]; cpa[i] = npa[i];
        if (PH16) cph16[i] = nph16[i]; else cph[i] = nph[i];
      }
    }
  }
  hlast[idx] = h;
}

extern "C" void kernel_launch(void* const* d_in, const int* in_sizes, int n_in,
                              void* d_out, int out_size, void* d_ws, size_t ws_size,
                              hipStream_t stream)
{
  const float* x  = (const float*)d_in[0];
  const float* h0 = (const float*)d_in[1];
  const float* Uc = (const float*)d_in[2];
  const float* wc = (const float*)d_in[3];
  const float* bc = (const float*)d_in[4];
  const float* Ua = (const float*)d_in[5];
  const float* wa = (const float*)d_in[6];
  const float* ba = (const float*)d_in[7];
  const float* Uh = (const float*)d_in[8];
  const float* bh = (const float*)d_in[9];

  float* y     = (float*)d_out;                 // [T,B,H]
  float* hlast = y + (size_t)T_SEQ * BH;        // [B,H]

  const size_t szP16 = (size_t)T_SEQ * BH * 2;     // 67,108,864 B
  const size_t szX16 = (size_t)M_TOT * IN_SZ * 2;  // 33,554,432 B
  const size_t szU16 = (size_t)HID * IN_SZ * 2;    // 1,048,576 B

  const size_t base = 2*szP16 + szX16 + 3*szU16;
  const bool ph_sep = ws_size >= base + szP16;     // separate fp16 ph buffer?

  char* w = (char*)d_ws;
  unsigned short* pc16 = (unsigned short*)w;
  unsigned short* pa16 = (unsigned short*)(w + szP16);
  unsigned short* xb   = (unsigned short*)(w + 2*szP16);
  unsigned short* U0b  = (unsigned short*)(w + 2*szP16 + szX16);
  unsigned short* U1b  = U0b + szU16/2;
  unsigned short* U2b  = U1b + szU16/2;
  unsigned short* ph16 = (unsigned short*)(w + base);   // only if ph_sep

  cvt_all<<<XBLK + 3*512, 256, 0, stream>>>(x, Uc, Ua, Uh, xb, U0b, U1b, U2b);

  void* phbuf = ph_sep ? (void*)ph16 : (void*)y;
  gemm3<<<1536, 512, 0, stream>>>(xb, U0b, U1b, U2b, bc, ba, bh,
                                  pc16, pa16, phbuf, ph_sep ? 1 : 0);

  if (ph_sep)
    scan_k<true><<<BH/256, 256, 0, stream>>>(pc16, pa16, (const void*)ph16,
                                             y, h0, wc, wa, hlast);
  else
    scan_k<false><<<BH/256, 256, 0, stream>>>(pc16, pa16, (const void*)y,
                                              y, h0, wc, wa, hlast);
}

// Round 2
// 372.209 us; speedup vs baseline: 1.1722x; 1.1139x over previous
//
#include <hip/hip_runtime.h>
#include <cstdint>
#include <cstddef>

#define T_SEQ 512
#define BATCH 64
#define IN_SZ 512
#define HID   1024
#define BH    (BATCH*HID)      /* 65536 */
#define M_TOT (T_SEQ*BATCH)    /* 32768 */
#define D_CH  16               /* scan chunk depth */

typedef float f32x4 __attribute__((ext_vector_type(4)));
typedef _Float16 f16x8 __attribute__((ext_vector_type(8)));

__device__ inline unsigned short f2h(float f){
  union { _Float16 h; unsigned short u; } v;
  v.h = (_Float16)f;            // RTNE
  return v.u;
}
__device__ inline float h2f(unsigned short s){
  union { unsigned short u; _Float16 h; } v; v.u = s;
  return (float)v.h;
}

__device__ inline float sigm_f(float x){ return 1.f/(1.f + __expf(-x)); }
__device__ inline float tanh_f(float x){ float e = __expf(2.f*x); return 1.f - 2.f/(e + 1.f); }

// async global->LDS, 16B per lane; lds base must be wave-uniform
__device__ inline void async16(const void* g, void* l){
  __builtin_amdgcn_global_load_lds(
      (__attribute__((address_space(1))) void*)g,
      (__attribute__((address_space(3))) void*)l,
      16, 0, 0);
}

// ---------- fused fp32 -> fp16 conversion for x, Uc, Ua, Uh ----------
#define XBLK 16384
__global__ __launch_bounds__(256) void cvt_all(
    const float* __restrict__ x,  const float* __restrict__ Uc,
    const float* __restrict__ Ua, const float* __restrict__ Uh,
    unsigned short* __restrict__ xb, unsigned short* __restrict__ U0,
    unsigned short* __restrict__ U1, unsigned short* __restrict__ U2)
{
  int b = blockIdx.x;
  const float* in; unsigned short* out; int i;
  if (b < XBLK){
    in = x; out = xb; i = b*256 + threadIdx.x;
  } else {
    int r = b - XBLK;
    int which = r >> 9;            // 0..2
    int lb = r & 511;
    i = lb*256 + threadIdx.x;
    in  = (which==0) ? Uc : (which==1) ? Ua : Uh;
    out = (which==0) ? U0 : (which==1) ? U1 : U2;
  }
  float4 v = ((const float4*)in)[i];
  ushort4 o;
  o.x = f2h(v.x); o.y = f2h(v.y); o.z = f2h(v.z); o.w = f2h(v.w);
  ((ushort4*)out)[i] = o;
}

// ---------- fused 3-projection GEMM: 256x256 tile, BK=64, 8 waves, phase-interleaved ----
// (identical to verified round-1 version; 127 us, MfmaUtil ~35%)
__global__ __launch_bounds__(512, 2) void gemm3(
    const unsigned short* __restrict__ xb,
    const unsigned short* __restrict__ U0,
    const unsigned short* __restrict__ U1,
    const unsigned short* __restrict__ U2,
    const float* __restrict__ b0, const float* __restrict__ b1, const float* __restrict__ b2,
    unsigned short* out0, unsigned short* out1, void* out2, int ph_f16)
{
  __shared__ __align__(16) unsigned char smem_raw[131072];

  const int tid  = threadIdx.x;
  const int wave = tid >> 6, lane = tid & 63;
  const int quad = lane >> 4, l16 = lane & 15;

  const int bid  = blockIdx.x;          // 0..1535
  const int xcd  = bid & 7;
  const int slot = bid >> 3;            // 0..191
  const int mbl  = slot / 12;           // 0..15
  const int inner= slot - mbl*12;       // 0..11
  const int mb   = xcd*16 + mbl;        // 0..127
  const int z    = inner % 3;
  const int nb   = inner / 3;           // 0..3

  const int m0 = mb * 256, n0 = nb * 256;
  const unsigned short* Um = (z==0) ? U0 : (z==1) ? U1 : U2;
  const float* bias        = (z==0) ? b0 : (z==1) ? b1 : b2;
  const int wm = wave >> 2, wn = wave & 3;   // 2 x 4 wave grid; per-wave 128x64

  const int laneRow = lane >> 2;
  const int cg8     = ((lane & 3) ^ ((lane >> 3) & 3)) << 3;
  const unsigned short* srcA = xb + (size_t)m0 * IN_SZ;
  const unsigned short* srcB = Um + (size_t)n0 * IN_SZ;

  const int cxa = l16*64 + ((quad ^ ((l16 >> 1) & 3)) << 4);

  auto stageA = [&](int tile, int kh){
    unsigned char* dst = smem_raw + (((tile & 1)*2 + kh) << 14);
#pragma unroll
    for (int j = 0; j < 2; ++j){
      const unsigned short* g = srcA + (size_t)((wave*2 + j)*16 + laneRow)*IN_SZ
                                + tile*64 + kh*32 + cg8;
      async16(g, dst + (wave*2 + j)*1024);
    }
  };
  auto stageB = [&](int tile, int kh){
    unsigned char* dst = smem_raw + 65536 + (((tile & 1)*2 + kh) << 14);
#pragma unroll
    for (int j = 0; j < 2; ++j){
      const unsigned short* g = srcB + (size_t)((wave*2 + j)*16 + laneRow)*IN_SZ
                                + tile*64 + kh*32 + cg8;
      async16(g, dst + (wave*2 + j)*1024);
    }
  };

  const f32x4 zf = {0.f, 0.f, 0.f, 0.f};
  f32x4 acc[8][4];
#pragma unroll
  for (int i = 0; i < 8; ++i)
#pragma unroll
    for (int j = 0; j < 4; ++j) acc[i][j] = zf;

  stageA(0,0); stageB(0,0); stageA(0,1); stageB(0,1);
  stageA(1,0); stageB(1,0); stageA(1,1);
  asm volatile("s_waitcnt vmcnt(10)" ::: "memory");
  __builtin_amdgcn_s_barrier();

#define CLUSTER(B0_, B1_, N0_, N1_)                                                      \
  __builtin_amdgcn_s_barrier();                                                          \
  asm volatile("s_waitcnt lgkmcnt(0)" ::: "memory");                                     \
  __builtin_amdgcn_s_setprio(1);                                                         \
  _Pragma("unroll")                                                                      \
  for (int im_ = 0; im_ < 8; ++im_){                                                     \
    acc[im_][N0_] = __builtin_amdgcn_mfma_f32_16x16x32_f16(a0[im_], B0_, acc[im_][N0_], 0,0,0); \
    acc[im_][N1_] = __builtin_amdgcn_mfma_f32_16x16x32_f16(a0[im_], B1_, acc[im_][N1_], 0,0,0); \
  }                                                                                      \
  __builtin_amdgcn_s_setprio(0);                                                         \
  __builtin_amdgcn_s_barrier();

  f16x8 a0[8];
#pragma unroll
  for (int g = 0; g < 8; ++g){
    const int buf = g & 1;
    const unsigned char* Ab0 = smem_raw + ((buf*2 + 0) << 14);
    const unsigned char* Ab1 = smem_raw + ((buf*2 + 1) << 14);
    const unsigned char* Bb0 = smem_raw + 65536 + ((buf*2 + 0) << 14);
    const unsigned char* Bb1 = smem_raw + 65536 + ((buf*2 + 1) << 14);

    // ---- p1: ks0, n-frags 0,1
#pragma unroll
    for (int im = 0; im < 8; ++im)
      a0[im] = *(const f16x8*)(Ab0 + wm*8192 + im*1024 + cxa);
    f16x8 q0 = *(const f16x8*)(Bb0 + wn*4096 + 0*1024 + cxa);
    f16x8 q1 = *(const f16x8*)(Bb0 + wn*4096 + 1*1024 + cxa);
    if (g < 7) stageB(g+1, 1);
    CLUSTER(q0, q1, 0, 1)

    // ---- p2: ks0, n-frags 2,3
    f16x8 q2 = *(const f16x8*)(Bb0 + wn*4096 + 2*1024 + cxa);
    f16x8 q3 = *(const f16x8*)(Bb0 + wn*4096 + 3*1024 + cxa);
    if (g < 6) stageA(g+2, 0);
    if (g < 6)      { asm volatile("s_waitcnt vmcnt(10)" ::: "memory"); }
    else if (g == 6){ asm volatile("s_waitcnt vmcnt(8)"  ::: "memory"); }
    else            { asm volatile("s_waitcnt vmcnt(0)"  ::: "memory"); }
    CLUSTER(q2, q3, 2, 3)

    // ---- p3: ks1, n-frags 0,1
#pragma unroll
    for (int im = 0; im < 8; ++im)
      a0[im] = *(const f16x8*)(Ab1 + wm*8192 + im*1024 + cxa);
    q0 = *(const f16x8*)(Bb1 + wn*4096 + 0*1024 + cxa);
    q1 = *(const f16x8*)(Bb1 + wn*4096 + 1*1024 + cxa);
    if (g < 6) stageB(g+2, 0);
    CLUSTER(q0, q1, 0, 1)

    // ---- p4: ks1, n-frags 2,3
    q2 = *(const f16x8*)(Bb1 + wn*4096 + 2*1024 + cxa);
    q3 = *(const f16x8*)(Bb1 + wn*4096 + 3*1024 + cxa);
    if (g < 6) stageA(g+2, 1);
    if (g < 6)      { asm volatile("s_waitcnt vmcnt(10)" ::: "memory"); }
    else if (g == 6){ asm volatile("s_waitcnt vmcnt(4)"  ::: "memory"); }
    CLUSTER(q2, q3, 2, 3)
  }
#undef CLUSTER

  float bv[4];
#pragma unroll
  for (int in = 0; in < 4; ++in) bv[in] = bias[n0 + wn*64 + in*16 + l16];

  if (z == 2 && !ph_f16) {
    float* o32 = (float*)out2;
#pragma unroll
    for (int im = 0; im < 8; ++im)
#pragma unroll
      for (int r = 0; r < 4; ++r){
        int grow = m0 + wm*128 + im*16 + quad*4 + r;
        size_t rb = (size_t)grow * HID;
#pragma unroll
        for (int in = 0; in < 4; ++in)
          o32[rb + n0 + wn*64 + in*16 + l16] = acc[im][in][r] + bv[in];
      }
    return;
  }

  unsigned short* op = (z==0) ? out0 : (z==1) ? out1 : (unsigned short*)out2;
  unsigned short* sw = (unsigned short*)smem_raw + wave*4608;
#pragma unroll
  for (int h = 0; h < 2; ++h){
#pragma unroll
    for (int i4 = 0; i4 < 4; ++i4){
      int im = h*4 + i4;
#pragma unroll
      for (int r = 0; r < 4; ++r){
        int lr = i4*16 + quad*4 + r;
#pragma unroll
        for (int in = 0; in < 4; ++in)
          sw[lr*72 + in*16 + l16] = f2h(acc[im][in][r] + bv[in]);
      }
    }
    asm volatile("s_waitcnt lgkmcnt(0)" ::: "memory");
#pragma unroll
    for (int i = 0; i < 8; ++i){
      int lr = i*8 + (lane >> 3);
      int ch = lane & 7;
      uint4 v = *(const uint4*)(sw + lr*72 + ch*8);
      int grow = m0 + wm*128 + h*64 + lr;
      *(uint4*)(op + (size_t)grow*HID + n0 + wn*64 + ch*8) = v;
    }
    if (h == 0) asm volatile("s_waitcnt lgkmcnt(0)" ::: "memory");
  }
}

// ---------- elementwise recurrence, v2: block-cooperative LDS staging ----------
// 256 blocks x 256 threads; thread owns one (b,h) column. 1 wave/SIMD (parallelism-
// capped), so BW must come from outstanding async loads: per chunk the block issues
// 24KB of global_load_lds (1KB/instr) into a double-buffered LDS tile, counted
// vmcnt(16) across the barrier (16 = this chunk's y-stores, the youngest vmem ops,
// so the wait proves all staging loads landed without draining stores).
// LDS read pattern: byte addr t*512 + tid*2 -> 2 lanes/bank = conflict-free.
template <bool PH16>
__global__ __launch_bounds__(256) void scan_k(
    const unsigned short* __restrict__ pc, const unsigned short* __restrict__ pa,
    const void* __restrict__ phv,
    float* __restrict__ y,
    const float* __restrict__ h0, const float* __restrict__ wc, const float* __restrict__ wa,
    float* __restrict__ hlast)
{
  __shared__ __align__(16) unsigned char sm[65536];
  const int tid  = threadIdx.x;
  const int wave = tid >> 6, lane = tid & 63;
  const int col0 = blockIdx.x * 256;
  const int idx  = col0 + tid;
  const int hidx = idx & (HID - 1);

  float h = h0[idx];
  const float wcv = wc[hidx], wav = wa[hidx];
  const unsigned short* ph16 = (const unsigned short*)phv;
  const float*          ph32 = (const float*)phv;

  // LDS: pc [2][8KB] @0, pa [2][8KB] @16K, ph [2][8KB fp16 | 16KB fp32] @32K
  unsigned char* pcL = sm;
  unsigned char* paL = sm + 16384;
  unsigned char* phL = sm + 32768;

  auto stage = [&](int c){
    const int b  = c & 1;
    const int t0 = c * D_CH;
    // u16 streams: each issue covers 2 rows (512B/row); wave w, j -> rows w*2+j*8 {,+1}
#pragma unroll
    for (int j = 0; j < 2; ++j){
      const int tr  = wave*2 + j*8;
      const int row = tr + (lane >> 5);
      const int ce  = (lane & 31) * 8;          // ushort col within 256-col slab
      async16(pc + (size_t)(t0+row)*BH + col0 + ce, pcL + b*8192 + tr*512);
      async16(pa + (size_t)(t0+row)*BH + col0 + ce, paL + b*8192 + tr*512);
    }
    if (PH16){
#pragma unroll
      for (int j = 0; j < 2; ++j){
        const int tr  = wave*2 + j*8;
        const int row = tr + (lane >> 5);
        const int ce  = (lane & 31) * 8;
        async16(ph16 + (size_t)(t0+row)*BH + col0 + ce, phL + b*8192 + tr*512);
      }
    } else {
      // fp32 stream: 1KB/row, one issue per row; wave w, j -> row w + j*4
#pragma unroll
      for (int j = 0; j < 4; ++j){
        const int t = wave + j*4;
        async16(ph32 + (size_t)(t0+t)*BH + col0 + lane*4, phL + b*16384 + t*1024);
      }
    }
  };

  stage(0);
  asm volatile("s_waitcnt vmcnt(0)" ::: "memory");
  __builtin_amdgcn_s_barrier();
  __builtin_amdgcn_sched_barrier(0);

  constexpr int NC = T_SEQ / D_CH;
  for (int c = 0; c < NC; ++c){
    if (c + 1 < NC) stage(c + 1);          // fill buf (c+1)&1 while computing buf c&1
    const int b  = c & 1;
    const int t0 = c * D_CH;
    const unsigned short* pcb   = (const unsigned short*)(pcL + b*8192)  + tid;
    const unsigned short* pab   = (const unsigned short*)(paL + b*8192)  + tid;
    const unsigned short* phb16 = (const unsigned short*)(phL + b*8192)  + tid;
    const float*          phb32 = (const float*)(phL + b*16384) + tid;
#pragma unroll
    for (int i = 0; i < D_CH; ++i){
      float pcv = h2f(pcb[i*256]);
      float pav = h2f(pab[i*256]);
      float ph_ = PH16 ? h2f(phb16[i*256]) : phb32[i*256];
      float cc = sigm_f(pcv + wcv*h);
      float a  = 1.f + tanh_f(pav + wav*h);
      float hc = tanh_f(ph_ + a*h);
      h = cc*h + (1.f - cc)*hc;
      y[(size_t)(t0 + i)*BH + idx] = h;
    }
    if (c + 1 < NC){
      // youngest 16 vmem ops are this chunk's y-stores; <=16 outstanding proves
      // all staging loads (older) have landed. Never drain to 0 in the loop.
      asm volatile("s_waitcnt vmcnt(16)" ::: "memory");
      __builtin_amdgcn_s_barrier();
      __builtin_amdgcn_sched_barrier(0);   // rule #18: pin next chunk's ds_reads
    }
  }
  hlast[idx] = h;
}

extern "C" void kernel_launch(void* const* d_in, const int* in_sizes, int n_in,
                              void* d_out, int out_size, void* d_ws, size_t ws_size,
                              hipStream_t stream)
{
  const float* x  = (const float*)d_in[0];
  const float* h0 = (const float*)d_in[1];
  const float* Uc = (const float*)d_in[2];
  const float* wc = (const float*)d_in[3];
  const float* bc = (const float*)d_in[4];
  const float* Ua = (const float*)d_in[5];
  const float* wa = (const float*)d_in[6];
  const float* ba = (const float*)d_in[7];
  const float* Uh = (const float*)d_in[8];
  const float* bh = (const float*)d_in[9];

  float* y     = (float*)d_out;                 // [T,B,H]
  float* hlast = y + (size_t)T_SEQ * BH;        // [B,H]

  const size_t szP16 = (size_t)T_SEQ * BH * 2;     // 67,108,864 B
  const size_t szX16 = (size_t)M_TOT * IN_SZ * 2;  // 33,554,432 B
  const size_t szU16 = (size_t)HID * IN_SZ * 2;    // 1,048,576 B

  const size_t base = 2*szP16 + szX16 + 3*szU16;
  const bool ph_sep = ws_size >= base + szP16;     // separate fp16 ph buffer?

  char* w = (char*)d_ws;
  unsigned short* pc16 = (unsigned short*)w;
  unsigned short* pa16 = (unsigned short*)(w + szP16);
  unsigned short* xb   = (unsigned short*)(w + 2*szP16);
  unsigned short* U0b  = (unsigned short*)(w + 2*szP16 + szX16);
  unsigned short* U1b  = U0b + szU16/2;
  unsigned short* U2b  = U1b + szU16/2;
  unsigned short* ph16 = (unsigned short*)(w + base);   // only if ph_sep

  cvt_all<<<XBLK + 3*512, 256, 0, stream>>>(x, Uc, Ua, Uh, xb, U0b, U1b, U2b);

  void* phbuf = ph_sep ? (void*)ph16 : (void*)y;
  gemm3<<<1536, 512, 0, stream>>>(xb, U0b, U1b, U2b, bc, ba, bh,
                                  pc16, pa16, phbuf, ph_sep ? 1 : 0);

  if (ph_sep)
    scan_k<true><<<BH/256, 256, 0, stream>>>(pc16, pa16, (const void*)ph16,
                                             y, h0, wc, wa, hlast);
  else
    scan_k<false><<<BH/256, 256, 0, stream>>>(pc16, pa16, (const void*)y,
                                              y, h0, wc, wa, hlast);
}